// Round 10
// baseline (25910.059 us; speedup 1.0000x reference)
//
#include <hip/hip_runtime.h>

// FPS: 2 batches x 131072 pts, 4096 samples/batch, seed = point 0.
// R10: SHRINK THE SYNC GROUP. 8 blocks/batch x 1024 threads (16 waves),
// PPT=16 unchanged. Global round: 8 slot stores -> 4 cache lines (was 16),
// wave0-only polling -> 8 pollers/batch (was 128), skew = max-of-8 (was 32).
// Intra-block 16-wave reduce via tagged LDS (CU-local): siblings post
// partials, wave0 collects per-lane, winner fanned back via one tagged LDS
// record. Pure SYSTEM scope (sc0 sc1) — L2-scope sync measured SLOWER under
// spin load in R8/R9 despite lower HBM traffic. No placement/timing bets,
// no timeouts: liveness is structural (R3 proof).
// Key = dist_bits<<32 | step<<17 | (0x1FFFF - idx): u64 max ==
// (dist desc, idx asc) == jnp.argmax first-index tiebreak. Exact fp32
// (contract off, __fmul_rn/__fadd_rn) matches the numpy reference.
// Ring safety (RING=4, fire-and-forget): block B stores s+4 only after
// passing poll(s+3) => every block stored s+3 => everyone passed poll(s)
// => all tag-s reads done. B passes poll(s) only after seeing its OWN slot
// fresh (lanes 2*blk, 2*blk+1 of wave0 check it) => own-store visibility.
// LDS safety: sibling posts partial(s+1) only after consuming winner(s);
// wave0 publishes winner(s+1) only after collecting all partials(s+1);
// tags (step) make stale reads impossible. Zero/0xAA never tag-match.

#define NB    8       // blocks per batch
#define TPB   1024    // 16 waves
#define PPT   16      // 8*1024*16 = 131072
#define NPB   131072
#define MSAMP 4096
#define RING  4

typedef unsigned long long u64;
typedef unsigned int u32;
typedef __attribute__((ext_vector_type(4))) u32 u32x4;

__device__ __forceinline__ u32x4 ld16_sys(const u32* p) {
  u32x4 r;
  asm volatile("global_load_dwordx4 %0, %1, off sc0 sc1\n\ts_waitcnt vmcnt(0)"
               : "=v"(r) : "v"(p) : "memory");
  return r;
}
__device__ __forceinline__ void st16_sys(u32* p, u32x4 v) {  // fire-and-forget
  asm volatile("global_store_dwordx4 %0, %1, off sc0 sc1"
               :: "v"(p), "v"(v) : "memory");
}

__global__ __launch_bounds__(TPB, 1)
void fps_kernel(const float4* __restrict__ pts, float* __restrict__ out,
                u32* __restrict__ slots)
{
#pragma clang fp contract(off)
  const int batch = blockIdx.x >> 3;         // / NB
  const int blk   = blockIdx.x & (NB - 1);
  const int tid   = threadIdx.x;
  const int lane  = tid & 63;
  const int wv    = tid >> 6;                // 0..15
  const float4* bpts = pts + (size_t)batch * NPB;
  u32* bslots = slots + (size_t)batch * (RING * NB * 8);  // 8 u32 per slot

  __shared__ u64   s_pkey[16];               // tagged sibling partials
  __shared__ float s_pcx[16], s_pcy[16], s_pcz[16];
  __shared__ u32   s_wtag, s_wx, s_wy, s_wz; // tagged winner record

  if (tid < 16) s_pkey[tid] = 0ull;          // tag 0 never matches s>=1
  if (tid == 0) s_wtag = 0u;
  __syncthreads();                           // only barrier in the kernel

  const int base = blk * (TPB * PPT);

  float px[PPT], py[PPT], pz[PPT], dist[PPT];
#pragma unroll
  for (int k = 0; k < PPT; ++k) {
    float4 p = bpts[base + k * TPB + tid];   // row = (b, x, y, z)
    px[k] = p.y; py[k] = p.z; pz[k] = p.w;
    dist[k] = __builtin_inff();              // min(inf, d) == d bit-exactly
  }

  float4 seed = bpts[0];
  float sx = seed.y, sy = seed.z, sz = seed.w;
  if (blk == 0 && wv == 0 && lane == 0) {
    float4 o; o.x = (float)batch; o.y = sx; o.z = sy; o.w = sz;
    *(float4*)(out + (size_t)batch * MSAMP * 4) = o;
  }

  for (int s = 1; s < MSAMP; ++s) {
    // ---- fused dist update + per-thread argmax, coords tracked ----
    float bestd = -1.0f, bx = 0.f, by = 0.f, bz = 0.f; int besti = 0;
#pragma unroll
    for (int k = 0; k < PPT; ++k) {
      float dx = px[k] - sx, dy = py[k] - sy, dz = pz[k] - sz;
      float d2 = __fadd_rn(__fadd_rn(__fmul_rn(dx, dx), __fmul_rn(dy, dy)),
                           __fmul_rn(dz, dz));
      float nd = fminf(dist[k], d2);
      dist[k] = nd;
      if (nd > bestd) {                      // strict '>': first-index tiebreak
        bestd = nd; besti = base + k * TPB + tid;
        bx = px[k]; by = py[k]; bz = pz[k];
      }
    }

    u64 pv0 = ((u64)__float_as_uint(bestd) << 32) | ((u64)s << 17) |
              (u64)(0x1FFFF - besti);
    u64 pv = pv0;
#pragma unroll
    for (int m = 32; m >= 1; m >>= 1) {
      u64 o = __shfl_xor(pv, m, 64);
      if (o > pv) pv = o;
    }
    int wl = __ffsll(__ballot(pv0 == pv)) - 1;   // keys unique (idx embedded)
    float wx = __shfl(bx, wl, 64), wy = __shfl(by, wl, 64),
          wz = __shfl(bz, wl, 64);

    if (wv != 0) {
      // ---- sibling wave: post tagged partial, spin on winner record ----
      if (lane == 0) {
        s_pcx[wv] = wx; s_pcy[wv] = wy; s_pcz[wv] = wz;
        __hip_atomic_store(&s_pkey[wv], pv, __ATOMIC_RELEASE,
                           __HIP_MEMORY_SCOPE_WORKGROUP);
      }
      while (__hip_atomic_load(&s_wtag, __ATOMIC_ACQUIRE,
                               __HIP_MEMORY_SCOPE_WORKGROUP) != (u32)s)
        __builtin_amdgcn_s_sleep(1);         // don't steal wave0 issue slots
      sx = __uint_as_float(s_wx);
      sy = __uint_as_float(s_wy);
      sz = __uint_as_float(s_wz);
      continue;
    }

    // ---- wave0: collect 16 tagged partials per-lane (incl. own) ----
    if (lane == 0) {
      s_pcx[0] = wx; s_pcy[0] = wy; s_pcz[0] = wz;
      __hip_atomic_store(&s_pkey[0], pv, __ATOMIC_RELEASE,
                         __HIP_MEMORY_SCOPE_WORKGROUP);
    }
    u64 pk;
    for (;;) {
      pk = (lane < 16)
         ? __hip_atomic_load(&s_pkey[lane], __ATOMIC_ACQUIRE,
                             __HIP_MEMORY_SCOPE_WORKGROUP)
         : ~0ull;
      bool ok = (lane >= 16) || ((u32)((pk >> 17) & 0x7FFF) == (u32)s);
      if (__ballot(ok) == ~0ull) break;
    }
    // block argmax over 16 partials (lanes 16..63 hold 0)
    u64 bk = (lane < 16) ? pk : 0ull;
#pragma unroll
    for (int m = 32; m >= 1; m >>= 1) {
      u64 o = __shfl_xor(bk, m, 64);
      if (o > bk) bk = o;
    }
    int bi = __ffsll(__ballot((lane < 16) && pk == bk)) - 1;  // winner wave

    u32* ring = bslots + (size_t)(s & (RING - 1)) * (NB * 8);
    if (lane < 2) {
      float cx = s_pcx[bi], cy = s_pcy[bi], cz = s_pcz[bi];
      u32x4 q;
      if (lane == 0) {                       // quad0: key(lo=tag|idx,hi=dist)+x,y
        q.x = (u32)(bk & 0xFFFFFFFFull); q.y = (u32)(bk >> 32);
        q.z = __float_as_uint(cx);        q.w = __float_as_uint(cy);
      } else {                               // quad1: tag + z
        q.x = (u32)s; q.y = __float_as_uint(cz); q.z = 0u; q.w = 0u;
      }
      st16_sys(ring + blk * 8 + lane * 4, q);  // fire-and-forget
    }

    // ---- poll (wave0 only): lane L reads quad L&15 (4 lines total) ----
    const int Lq = lane & 15;                // slot Lq>>1, half Lq&1
    const u32* pp = ring + Lq * 4;
    u32x4 q;
    for (;;) {
      q = ld16_sys(pp);
      bool ok = ((Lq & 1) == 0) ? ((q.x >> 17) == (u32)s) : (q.x == (u32)s);
      if (__ballot(ok) == ~0ull) break;
    }

    // ---- cross-block argmax + register-resident coord extraction ----
    u64 key = ((Lq & 1) == 0) ? (((u64)q.y << 32) | (u64)q.x) : 0ull;
    u64 w = key;
#pragma unroll
    for (int m = 32; m >= 1; m >>= 1) {
      u64 o = __shfl_xor(w, m, 64);
      if (o > w) w = o;
    }
    // lowest matching lane is canonical (lanes 0..15 hold quads 0..15)
    int wl2 = __ffsll(__ballot(key == w && ((Lq & 1) == 0))) - 1;
    sx = __shfl(__uint_as_float(q.z), wl2, 64);      // x from quad0 lane
    sy = __shfl(__uint_as_float(q.w), wl2, 64);      // y from quad0 lane
    sz = __shfl(__uint_as_float(q.y), wl2 + 1, 64);  // z from quad1 lane

    // ---- publish winner to sibling waves (tagged LDS record) ----
    if (lane == 0) {
      s_wx = __float_as_uint(sx); s_wy = __float_as_uint(sy);
      s_wz = __float_as_uint(sz);
      __hip_atomic_store(&s_wtag, (u32)s, __ATOMIC_RELEASE,
                         __HIP_MEMORY_SCOPE_WORKGROUP);
      if (blk == 0) {
        float4 o; o.x = (float)batch; o.y = sx; o.z = sy; o.w = sz;
        *(float4*)(out + (size_t)(batch * MSAMP + s) * 4) = o;
      }
    }
  }
}

extern "C" void kernel_launch(void* const* d_in, const int* in_sizes, int n_in,
                              void* d_out, int out_size, void* d_ws, size_t ws_size,
                              hipStream_t stream) {
  const float4* pts = (const float4*)d_in[0];
  float* out = (float*)d_out;
  u32* slots = (u32*)d_ws;

  // Zero both batches' slot rings (2 KB): poisoned tags never validate.
  hipMemsetAsync(d_ws, 0, (size_t)2 * RING * NB * 32, stream);

  dim3 grid(2 * NB), block(TPB);
  hipLaunchKernelGGL(fps_kernel, grid, block, 0, stream, pts, out, slots);
}

// Round 11
// 11432.320 us; speedup vs baseline: 2.2664x; 2.2664x over previous
//
#include <hip/hip_runtime.h>

// FPS: 2 batches x 131072 pts, 4096 samples/batch, seed = point 0.
// R11 = R3's proven protocol with ONE change: slot publication uses
// fire-and-forget SYSTEM-SCOPE ATOMIC SWAPS (global_atomic_swap_x2 sc1,
// no return) instead of plain sc0sc1 stores. Theory: plain stores drain
// lazily through L2 write-through to MALL (~2000+cyc visibility lag);
// atomics execute AT the memory-side cache (~450cyc one-way visibility).
// Slot = 4 x u64, each independently self-validating (arrival order of
// the 4 packets is arbitrary):
//   A = dist<<32 | s<<17 | (0x1FFFF - idx)   (tag in bits 17..31)
//   B = s<<32 | x_bits,  C = s<<32 | y_bits,  D = s<<32 | z_bits
// u64-max of A == (dist desc, idx asc) == jnp.argmax first-index tiebreak.
// Exact fp32 (contract off, __fmul_rn/__fadd_rn) matches numpy bitwise.
// Poll layout unchanged from R3: 32 slots x 32B = 16 lines; lane L reads
// 16B at offset L*16 (even lane: A,B; odd lane: C,D); winner coords
// extracted via shfl from poll registers (no dependent global load).
// Compute shape unchanged: 32 blocks x 256 thr (1 wave/SIMD), PPT=16,
// all coords+dists register-resident. NO scope speculation, NO placement
// bets, NO group shrink (R8-R10 all falsified those directions).
// Ring safety (RING=4, f&f swaps): block B publishes s+4 only after
// passing poll(s+3) => every block published s+3 => everyone passed
// poll(s) => all tag-s reads done before any tag-(s+4) overwrite. B
// passes poll(s) only after seeing its OWN slot fresh => own-publish
// visibility. Zero/0xAA-poisoned slots never tag-match (s in 1..4095).

#define NB    32
#define TPB   256
#define PPT   16      // 32*256*16 = 131072
#define NPB   131072
#define MSAMP 4096
#define RING  4

typedef unsigned long long u64;
typedef unsigned int u32;
typedef __attribute__((ext_vector_type(4))) u32 u32x4;

__device__ __forceinline__ u32x4 ld16_sys(const u32* p) {
  u32x4 r;
  asm volatile("global_load_dwordx4 %0, %1, off sc0 sc1\n\ts_waitcnt vmcnt(0)"
               : "=v"(r) : "v"(p) : "memory");
  return r;
}

__global__ __launch_bounds__(TPB, 1)
void fps_kernel(const float4* __restrict__ pts, float* __restrict__ out,
                u64* __restrict__ slots)
{
#pragma clang fp contract(off)
  const int batch = blockIdx.x >> 5;
  const int blk   = blockIdx.x & (NB - 1);
  const int tid   = threadIdx.x;
  const int lane  = tid & 63;
  const int wv    = tid >> 6;
  const float4* bpts = pts + (size_t)batch * NPB;
  u64* bslots = slots + (size_t)batch * (RING * NB * 4);  // 4 u64 per slot

  __shared__ u64   s_key[4];
  __shared__ float s_cx[4], s_cy[4], s_cz[4];

  const int base = blk * (TPB * PPT);

  float px[PPT], py[PPT], pz[PPT], dist[PPT];
#pragma unroll
  for (int k = 0; k < PPT; ++k) {
    float4 p = bpts[base + k * TPB + tid];   // row = (b, x, y, z)
    px[k] = p.y; py[k] = p.z; pz[k] = p.w;
    dist[k] = __builtin_inff();              // min(inf, d) == d bit-exactly
  }

  float4 seed = bpts[0];
  float sx = seed.y, sy = seed.z, sz = seed.w;
  if (blk == 0 && wv == 0 && lane == 0) {
    float4 o; o.x = (float)batch; o.y = sx; o.z = sy; o.w = sz;
    *(float4*)(out + (size_t)batch * MSAMP * 4) = o;
  }

  for (int s = 1; s < MSAMP; ++s) {
    // ---- fused dist update + per-thread argmax, coords tracked ----
    float bestd = -1.0f, bx = 0.f, by = 0.f, bz = 0.f; int besti = 0;
#pragma unroll
    for (int k = 0; k < PPT; ++k) {
      float dx = px[k] - sx, dy = py[k] - sy, dz = pz[k] - sz;
      float d2 = __fadd_rn(__fadd_rn(__fmul_rn(dx, dx), __fmul_rn(dy, dy)),
                           __fmul_rn(dz, dz));
      float nd = fminf(dist[k], d2);
      dist[k] = nd;
      if (nd > bestd) {                      // strict '>': first-index tiebreak
        bestd = nd; besti = base + k * TPB + tid;
        bx = px[k]; by = py[k]; bz = pz[k];
      }
    }

    u64 pv0 = ((u64)__float_as_uint(bestd) << 32) | ((u64)s << 17) |
              (u64)(0x1FFFF - besti);
    u64 pv = pv0;
#pragma unroll
    for (int m = 32; m >= 1; m >>= 1) {
      u64 o = __shfl_xor(pv, m, 64);
      if (o > pv) pv = o;
    }
    int wl = __ffsll(__ballot(pv0 == pv)) - 1;   // keys unique (idx embedded)
    float wx = __shfl(bx, wl, 64), wy = __shfl(by, wl, 64),
          wz = __shfl(bz, wl, 64);
    if (lane == 0) { s_key[wv] = pv; s_cx[wv] = wx; s_cy[wv] = wy; s_cz[wv] = wz; }
    __syncthreads();                         // one barrier per step

    u64* ring = bslots + (size_t)(s & (RING - 1)) * (NB * 4);
    if (wv == 0 && lane < 4) {
      // 4-way block reduce from LDS (redundant across lanes 0..3)
      u64 k0 = s_key[0], k1 = s_key[1], k2 = s_key[2], k3 = s_key[3];
      int bi = 0; u64 bk = k0;
      if (k1 > bk) { bk = k1; bi = 1; }
      if (k2 > bk) { bk = k2; bi = 2; }
      if (k3 > bk) { bk = k3; bi = 3; }
      u64 v;
      if      (lane == 0) v = bk;                                      // A
      else if (lane == 1) v = ((u64)(u32)s << 32) |
                              (u64)__float_as_uint(s_cx[bi]);          // B
      else if (lane == 2) v = ((u64)(u32)s << 32) |
                              (u64)__float_as_uint(s_cy[bi]);          // C
      else                v = ((u64)(u32)s << 32) |
                              (u64)__float_as_uint(s_cz[bi]);          // D
      // Fire-and-forget system-scope swap: executes at the memory-side
      // cache -> visible in ~one-way latency, no writeback laziness.
      (void)__hip_atomic_exchange(&ring[blk * 4 + lane], v,
                                  __ATOMIC_RELAXED,
                                  __HIP_MEMORY_SCOPE_SYSTEM);
    }

    // ---- poll: lane L reads 16B at offset L*16 (even: A,B; odd: C,D) ----
    const u32* pp = (const u32*)ring + lane * 4;
    u32x4 q;
    for (;;) {
      q = ld16_sys(pp);
      bool ok = ((lane & 1) == 0)
              ? (((q.x >> 17) & 0x7FFFu) == (u32)s && q.w == (u32)s)
              : (q.y == (u32)s && q.w == (u32)s);
      if (__ballot(ok) == ~0ull) break;
    }

    // ---- cross-block argmax + register-resident coord extraction ----
    // even lane: q = {A_lo, A_hi, x_bits, s}; odd lane: q = {y, s, z, s}
    u64 key = ((lane & 1) == 0) ? (((u64)q.y << 32) | (u64)q.x) : 0ull;
    u64 w = key;
#pragma unroll
    for (int m = 32; m >= 1; m >>= 1) {
      u64 o = __shfl_xor(w, m, 64);
      if (o > w) w = o;
    }
    int wl2 = __ffsll(__ballot(key == w && ((lane & 1) == 0))) - 1;
    sx = __shfl(__uint_as_float(q.z), wl2, 64);      // x from even lane
    sy = __shfl(__uint_as_float(q.x), wl2 + 1, 64);  // y from odd lane
    sz = __shfl(__uint_as_float(q.z), wl2 + 1, 64);  // z from odd lane

    if (blk == 0 && wv == 0 && lane == 0) {
      float4 o; o.x = (float)batch; o.y = sx; o.z = sy; o.w = sz;
      *(float4*)(out + (size_t)(batch * MSAMP + s) * 4) = o;
    }
  }
}

extern "C" void kernel_launch(void* const* d_in, const int* in_sizes, int n_in,
                              void* d_out, int out_size, void* d_ws, size_t ws_size,
                              hipStream_t stream) {
  const float4* pts = (const float4*)d_in[0];
  float* out = (float*)d_out;
  u64* slots = (u64*)d_ws;

  // Zero both batches' slot rings (8 KB): poisoned tags never validate.
  hipMemsetAsync(d_ws, 0, (size_t)2 * RING * NB * 4 * sizeof(u64), stream);

  dim3 grid(2 * NB), block(TPB);
  hipLaunchKernelGGL(fps_kernel, grid, block, 0, stream, pts, out, slots);
}